// Round 4
// baseline (353.898 us; speedup 1.0000x reference)
//
#include <hip/hip_runtime.h>
#include <hip/hip_bf16.h>

// DiGCN forward, MI355X. B=8 S=1024 D=768 L=2.
// bf16 MFMA GEMMs (16x16x32), 2-phase LDS dbuf. Softmax normalizer dropped
// entirely (LayerNorm is invariant to per-row scaling — exact). Adjacency as
// packed bitmask. pa stored unsplit + masked diagonal bands. All tile outputs
// repacked through LDS for 256B-coalesced stores.

using bf16 = __hip_bfloat16;
typedef __attribute__((ext_vector_type(8))) short short8;   // 8 bf16 = 4 VGPR
typedef __attribute__((ext_vector_type(4))) float f32x4;    // MFMA C/D frag

#define B_ 8
#define S_ 1024
#define D_ 768
#define BS_ 8192
#define SS_ 1048576L
#define SD_ 786432L
#define DD_ 589824L

__device__ __forceinline__ void gload16(const void* g, void* l) {
  __builtin_amdgcn_global_load_lds((const __attribute__((address_space(1))) void*)g,
                                   (__attribute__((address_space(3))) void*)l, 16, 0, 0);
}

__device__ __forceinline__ f32x4 mfma16(short8 a, short8 b, f32x4 c) {
  return __builtin_amdgcn_mfma_f32_16x16x32_bf16(a, b, c, 0, 0, 0);
}

__device__ __forceinline__ float wave_sum(float v) {
  #pragma unroll
  for (int o = 32; o; o >>= 1) v += __shfl_xor(v, o);
  return v;
}

__device__ __forceinline__ short bfbits(float x) {
  bf16 h = __float2bfloat16(x);
  return *reinterpret_cast<short*>(&h);
}

// ---- LDS tile [128 rows][64 bf16], XOR-swizzled: chunk slot = chunk ^ (row&7).
// Staged via global_load_lds (linear dest, pre-swizzled global source, rule #21).
__device__ __forceinline__ void stage_tile(const bf16* g, long ld, int kt, short* s,
                                           int w, int lane) {
  #pragma unroll
  for (int i = 0; i < 4; ++i) {
    int rt = w * 32 + i * 8 + (lane >> 3);        // row within tile
    int ch = lane & 7;                            // 16B chunk slot within row
    const bf16* src = g + (long)rt * ld + (long)kt * 64 + ((ch ^ (rt & 7)) << 3);
    gload16((const void*)src, (void*)(s + (w * 32 + i * 8) * 64));
  }
}

__device__ __forceinline__ short8 read_frag(const short* s, int r0, int kk, int lane) {
  int r = r0 + (lane & 15);
  int c = (kk << 2) + (lane >> 4);                // 16B chunk index wanted
  return *(const short8*)((const char*)s + r * 128 + ((c ^ (r & 7)) << 4));
}

__device__ __forceinline__ void compute_tile(const short* As, const short* Bs,
                                             f32x4 acc[4][4], int lane, int wm, int wn) {
  #pragma unroll
  for (int kk = 0; kk < 2; ++kk) {
    short8 af[4], bfr[4];
    #pragma unroll
    for (int m = 0; m < 4; ++m) af[m] = read_frag(As, wm * 64 + m * 16, kk, lane);
    #pragma unroll
    for (int n = 0; n < 4; ++n) bfr[n] = read_frag(Bs, wn * 64 + n * 16, kk, lane);
    #pragma unroll
    for (int m = 0; m < 4; ++m)
      #pragma unroll
      for (int n = 0; n < 4; ++n)
        acc[m][n] = mfma16(af[m], bfr[n], acc[m][n]);
  }
}

// 2-phase double-buffered GEMM loop (T3-minimum): single A/B source pair.
__device__ __forceinline__ void gemm_db(const bf16* A, long lda, const bf16* Bm, long ldb,
                                        int kt0, int kt1, short (*L)[8192],
                                        f32x4 acc[4][4], int w, int lane, int wm, int wn) {
  stage_tile(A, lda, kt0, L[0], w, lane);
  stage_tile(Bm, ldb, kt0, L[1], w, lane);
  asm volatile("s_waitcnt vmcnt(0)");
  __syncthreads();
  int cur = 0;
  for (int kt = kt0; kt < kt1; ++kt) {
    if (kt + 1 < kt1) {
      stage_tile(A, lda, kt + 1, L[2 * (cur ^ 1)], w, lane);
      stage_tile(Bm, ldb, kt + 1, L[2 * (cur ^ 1) + 1], w, lane);
    }
    compute_tile(L[2 * cur], L[2 * cur + 1], acc, lane, wm, wn);
    asm volatile("s_waitcnt vmcnt(0)");
    __syncthreads();
    cur ^= 1;
  }
}

// LDS-repacked coalesced tile store: T[128][136] -> dst (128 rows x 128 cols bf16)
__device__ __forceinline__ void copy_out(const short* T, short* dst, long ldg, int tid) {
  #pragma unroll
  for (int q = 0; q < 8; ++q) {
    int id = q * 256 + tid;
    int r = id >> 4, chk = id & 15;
    short8 v = *(const short8*)(T + r * 136 + chk * 8);
    *(short8*)(dst + (long)r * ldg + chk * 8) = v;
  }
}

// ---- adjacency -> packed bitmask (one-time) ----
__global__ __launch_bounds__(256) void k_packadj(const float* __restrict__ adj,
                                                 unsigned long long* __restrict__ am) {
  int gw = (blockIdx.x * 256 + threadIdx.x) >> 6;   // global wave 0..2047
  int lane = threadIdx.x & 63;
  for (int it = 0; it < 64; ++it) {
    long base = ((long)(it * 2048 + gw)) * 64;
    float v = adj[base + lane];
    unsigned long long b = __ballot(v != 0.0f);
    if (lane == 0) am[base >> 6] = b;
  }
}

// ---- scores GEMM + fused exp/bitmask epilogue (unnormalized pa) ----
// off-diag blocks -> pa (unmasked); diagonal blocks -> masked U/L bands + diag.
__global__ __launch_bounds__(256) void k_scores(const bf16* __restrict__ hb,
                                                const unsigned* __restrict__ am,
                                                bf16* __restrict__ pa,
                                                bf16* __restrict__ paUb,
                                                bf16* __restrict__ paLb,
                                                float* __restrict__ diagpa,
                                                float scale) {
  __shared__ short L[4][8192];
  int b = blockIdx.z, bx = blockIdx.x, by = blockIdx.y;
  int tid = threadIdx.x, w = tid >> 6, lane = tid & 63, wm = w >> 1, wn = w & 1;
  const bf16* A = hb + (long)b * SD_ + (long)bx * 128 * D_;
  const bf16* Bp = hb + (long)b * SD_ + (long)by * 128 * D_;
  f32x4 acc[4][4] = {};
  gemm_db(A, D_, Bp, D_, 0, 12, L, acc, w, lane, wm, wn);
  bool dgb = (bx == by);
  short* T = (short*)L;
  int row0 = wm * 64, col0 = wn * 64;              // tile-local
  int rs_off = bx * 128, cs_off = by * 128;
  int npass = dgb ? 2 : 1;
  for (int pass = 0; pass < npass; ++pass) {
    if (pass) __syncthreads();                     // prev copy-out reads done
    #pragma unroll
    for (int m = 0; m < 4; ++m) {
      int rl0 = row0 + m * 16 + ((lane >> 4) << 2);
      #pragma unroll
      for (int j = 0; j < 4; ++j) {
        int rl = rl0 + j;
        int rglob = rs_off + rl;
        long rowg = (long)b * S_ + rglob;
        const unsigned* mrow = am + rowg * 32 + (cs_off >> 5) + (wn << 1);
        unsigned w0 = mrow[0], w1 = mrow[1];
        #pragma unroll
        for (int n = 0; n < 4; ++n) {
          int cl = col0 + n * 16 + (lane & 15);
          int cglob = cs_off + cl;
          unsigned wv = (n & 2) ? w1 : w0;
          int bit = (wv >> (((n & 1) << 4) + (lane & 15))) & 1;
          float p = __expf(acc[m][n][j] * scale);   // no max-sub: u bounded
          float pav = bit ? p : 0.f;
          if (dgb && pass == 0 && cglob == rglob) diagpa[rowg] = pav;
          bool keep = !dgb || (pass == 0 ? (cglob > rglob) : (cglob < rglob));
          T[rl * 136 + cl] = bfbits(keep ? pav : 0.f);
        }
      }
    }
    __syncthreads();
    short* dst; long ldg;
    if (!dgb)           { dst = (short*)pa   + (long)b * SS_ + (long)rs_off * S_ + cs_off; ldg = S_; }
    else if (pass == 0) { dst = (short*)paUb + (long)b * (S_ * 128L) + (long)rs_off * 128; ldg = 128; }
    else                { dst = (short*)paLb + (long)b * (S_ * 128L) + (long)rs_off * 128; ldg = 128; }
    copy_out(T, dst, ldg, tid);
  }
}

// ---- hl/hs/hr = hb @ W^T + bias; z=0->hlT (transposed), z=1->hs, z=2->hrT ----
__global__ __launch_bounds__(256) void k_proj(const bf16* __restrict__ hb,
                                              const bf16* __restrict__ Wb,
                                              const float* __restrict__ bl,
                                              const float* __restrict__ bs,
                                              const float* __restrict__ br,
                                              bf16* __restrict__ hlT,
                                              bf16* __restrict__ hsb,
                                              bf16* __restrict__ hrT) {
  __shared__ short L[4][8192];
  int z = blockIdx.z;
  int tid = threadIdx.x, w = tid >> 6, lane = tid & 63, wm = w >> 1, wn = w & 1;
  const bf16* A = hb + (long)blockIdx.x * 128 * D_;
  const bf16* Bp = Wb + (long)z * 2 * DD_ + (long)blockIdx.y * 128 * D_;
  f32x4 acc[4][4] = {};
  gemm_db(A, D_, Bp, D_, 0, 12, L, acc, w, lane, wm, wn);
  const float* bias = (z == 0) ? bl : (z == 1) ? bs : br;
  int rowg0 = blockIdx.x * 128, colg0 = blockIdx.y * 128;
  short* T = (short*)L;
  #pragma unroll
  for (int m = 0; m < 4; ++m) {
    int rl0 = wm * 64 + m * 16 + ((lane >> 4) << 2);
    #pragma unroll
    for (int n = 0; n < 4; ++n) {
      int cl = wn * 64 + n * 16 + (lane & 15);
      float bv = bias[colg0 + cl];
      #pragma unroll
      for (int j = 0; j < 4; ++j) {
        short v = bfbits(acc[m][n][j] + bv);
        if (z == 1) T[(rl0 + j) * 136 + cl] = v;   // row-major
        else        T[cl * 136 + rl0 + j] = v;     // transposed
      }
    }
  }
  __syncthreads();
  if (z == 1) {
    copy_out(T, (short*)hsb + (long)rowg0 * D_ + colg0, D_, tid);
  } else {
    short* outT = (short*)((z == 0) ? hlT : hrT);
    copy_out(T, outT + (long)colg0 * BS_ + rowg0, BS_, tid);
  }
}

// ---- ctx = pa@hl (upper) + diagpa*hs + pa@hr (lower); unnormalized (exact under LN) ----
__global__ __launch_bounds__(256) void k_ctx(const bf16* __restrict__ pa,
                                             const bf16* __restrict__ paUb,
                                             const bf16* __restrict__ paLb,
                                             const bf16* __restrict__ hlT,
                                             const bf16* __restrict__ hrT,
                                             const bf16* __restrict__ hsb,
                                             const float* __restrict__ diagpa,
                                             float* __restrict__ ctx) {
  __shared__ short L[4][8192];
  int b = blockIdx.z;
  int tid = threadIdx.x, w = tid >> 6, lane = tid & 63, wm = w >> 1, wn = w & 1;
  int rm = blockIdx.x * 128;
  int t = rm >> 6, ntU = 16 - t, nt = ntU + t + 2;
  const bf16* Af = pa + (long)b * SS_ + (long)rm * S_;
  const bf16* Ub = paUb + (long)b * (S_ * 128L) + (long)rm * 128;
  const bf16* Lb = paLb + (long)b * (S_ * 128L) + (long)rm * 128;
  const bf16* B1 = hlT + (long)blockIdx.y * 128 * BS_ + (long)b * S_;
  const bf16* B2 = hrT + (long)blockIdx.y * 128 * BS_ + (long)b * S_;
  f32x4 acc[4][4] = {};

  auto sel = [&](int q, const bf16*& Ap, long& la, int& kA, const bf16*& Bq, int& kB) {
    if (q < ntU) {
      int kt = t + q; Bq = B1; kB = kt;
      if (q < 2) { Ap = Ub; la = 128; kA = q; }
      else       { Ap = Af; la = S_;  kA = kt; }
    } else {
      int kt = q - ntU; Bq = B2; kB = kt;
      if (kt < t) { Ap = Af; la = S_;  kA = kt; }
      else        { Ap = Lb; la = 128; kA = kt - t; }
    }
  };

  { const bf16 *Ap, *Bq; long la; int kA, kB;
    sel(0, Ap, la, kA, Bq, kB);
    stage_tile(Ap, la, kA, L[0], w, lane);
    stage_tile(Bq, BS_, kB, L[1], w, lane); }
  asm volatile("s_waitcnt vmcnt(0)");
  __syncthreads();
  int cur = 0;
  for (int q = 0; q < nt; ++q) {
    if (q + 1 < nt) {
      const bf16 *Ap, *Bq; long la; int kA, kB;
      sel(q + 1, Ap, la, kA, Bq, kB);
      stage_tile(Ap, la, kA, L[2 * (cur ^ 1)], w, lane);
      stage_tile(Bq, BS_, kB, L[2 * (cur ^ 1) + 1], w, lane);
    }
    compute_tile(L[2 * cur], L[2 * cur + 1], acc, lane, wm, wn);
    asm volatile("s_waitcnt vmcnt(0)");
    __syncthreads();
    cur ^= 1;
  }

  int row0 = rm + wm * 64, col0 = blockIdx.y * 128 + wn * 64;
  #pragma unroll
  for (int m = 0; m < 4; ++m) {
    int r = row0 + m * 16 + ((lane >> 4) << 2);
    float dg[4];
    #pragma unroll
    for (int j = 0; j < 4; ++j) dg[j] = diagpa[(long)b * S_ + r + j];
    #pragma unroll
    for (int n = 0; n < 4; ++n) {
      int c = col0 + n * 16 + (lane & 15);
      #pragma unroll
      for (int j = 0; j < 4; ++j) {
        long gr = (long)b * S_ + r + j;
        float hv = __bfloat162float(hsb[gr * D_ + c]);
        ctx[gr * D_ + c] = acc[m][n][j] + dg[j] * hv;
      }
    }
  }
}

// ---- LayerNorm + ReLU ----
__global__ __launch_bounds__(256) void k_ln(const float* __restrict__ ctx,
                                            const float* __restrict__ g,
                                            const float* __restrict__ beta,
                                            float* __restrict__ outF,
                                            bf16* __restrict__ outB) {
  int wv = threadIdx.x >> 6, lane = threadIdx.x & 63;
  long row = (long)blockIdx.x * 4 + wv;
  const float* x = ctx + row * D_;
  float v[12]; float s = 0.f;
  #pragma unroll
  for (int k = 0; k < 12; ++k) { v[k] = x[k * 64 + lane]; s += v[k]; }
  s = wave_sum(s);
  float mean = s * (1.0f / 768.0f);
  float q = 0.f;
  #pragma unroll
  for (int k = 0; k < 12; ++k) { float d = v[k] - mean; q += d * d; }
  q = wave_sum(q);
  float inv = rsqrtf(fmaxf(q * (1.0f / 768.0f), 0.f) + 1e-12f);
  #pragma unroll
  for (int k = 0; k < 12; ++k) {
    int c = k * 64 + lane;
    float o = fmaxf((v[k] - mean) * inv * g[c] + beta[c], 0.f);
    if (outF) outF[row * D_ + c] = o;
    if (outB) outB[row * D_ + c] = __float2bfloat16(o);
  }
}

// ---- fp32 -> bf16 casts ----
__global__ __launch_bounds__(256) void k_castf(const float* __restrict__ in,
                                               bf16* __restrict__ out) {
  long idx = ((long)blockIdx.x * 256 + threadIdx.x) * 4;
  float4 f = *(const float4*)(in + idx);
  out[idx] = __float2bfloat16(f.x);
  out[idx + 1] = __float2bfloat16(f.y);
  out[idx + 2] = __float2bfloat16(f.z);
  out[idx + 3] = __float2bfloat16(f.w);
}

// cast all weights for both layers once: out layout [z][l][D][D]
__global__ __launch_bounds__(256) void k_castw(const float* __restrict__ wl,
                                               const float* __restrict__ ws_,
                                               const float* __restrict__ wr,
                                               bf16* __restrict__ out) {
  const float* src = (blockIdx.y == 0) ? wl : (blockIdx.y == 1) ? ws_ : wr;
  bf16* o = out + (long)blockIdx.y * 2 * DD_;      // [z][l=0..1][..]
  long idx = ((long)blockIdx.x * 256 + threadIdx.x) * 4;
  float4 f = *(const float4*)(src + idx);
  o[idx] = __float2bfloat16(f.x);
  o[idx + 1] = __float2bfloat16(f.y);
  o[idx + 2] = __float2bfloat16(f.z);
  o[idx + 3] = __float2bfloat16(f.w);
}

extern "C" void kernel_launch(void* const* d_in, const int* in_sizes, int n_in,
                              void* d_out, int out_size, void* d_ws, size_t ws_size,
                              hipStream_t stream) {
  const float* hidden = (const float*)d_in[0];
  const float* adj    = (const float*)d_in[1];
  const float* Wl     = (const float*)d_in[2];
  const float* bl     = (const float*)d_in[3];
  const float* Ws     = (const float*)d_in[4];
  const float* bs     = (const float*)d_in[5];
  const float* Wr     = (const float*)d_in[6];
  const float* br     = (const float*)d_in[7];
  const float* lnw    = (const float*)d_in[8];
  const float* lnb    = (const float*)d_in[9];
  float* out = (float*)d_out;

  char* ws = (char*)d_ws;
  bf16*     hb     = (bf16*)(ws);                  // [8192][768]        12.6 MB
  bf16*     hlT    = (bf16*)(ws + 12582912);       // [768][8192]
  bf16*     hrT    = (bf16*)(ws + 25165824);
  bf16*     hsb    = (bf16*)(ws + 37748736);       // [8192][768]
  bf16*     Wb     = (bf16*)(ws + 50331648);       // [3][2][768][768]    7.1 MB
  float*    diagpa = (float*)(ws + 57409536);      // [8192]
  unsigned* amask  = (unsigned*)(ws + 57442304);   // [8192][32] u32      1.0 MB
  bf16*     pa     = (bf16*)(ws + 58490880);       // [8][1024][1024]    16.8 MB
  bf16*     paUb   = (bf16*)(ws + 75268096);       // [8][1024][128]      2.1 MB
  bf16*     paLb   = (bf16*)(ws + 77365248);       // [8][1024][128]      2.1 MB
  float*    ctx    = (float*)(ws + 79462400);      // [8192][768] fp32   25.2 MB

  const float scale = 0.03608439182435161f;        // 1/sqrt(768)

  k_castf<<<6144, 256, 0, stream>>>(hidden, hb);
  k_castw<<<dim3(1152, 3), 256, 0, stream>>>(Wl, Ws, Wr, Wb);
  k_packadj<<<512, 256, 0, stream>>>(adj, (unsigned long long*)amask);
  for (int l = 0; l < 2; ++l) {
    k_scores<<<dim3(8, 8, B_), 256, 0, stream>>>(hb, amask, pa, paUb, paLb, diagpa, scale);
    k_proj<<<dim3(64, 6, 3), 256, 0, stream>>>(hb, Wb + (long)l * DD_, bl + l * D_,
                                               bs + l * D_, br + l * D_, hlT, hsb, hrT);
    k_ctx<<<dim3(8, 6, B_), 256, 0, stream>>>(pa, paUb, paLb, hlT, hrT, hsb, diagpa, ctx);
    k_ln<<<2048, 256, 0, stream>>>(ctx, lnw + l * D_, lnb + l * D_,
                                   (l == 1) ? out : nullptr,
                                   (l == 1) ? (bf16*)nullptr : hb);
  }
}